// Round 8
// baseline (198.438 us; speedup 1.0000x reference)
//
#include <hip/hip_runtime.h>

#define TT 140
#define BB 8192
#define HH 64
#define BT 16   // batch tile per block (MFMA N)
#define HS 72   // h stride in bf16 elems: 144 B -> 16B-aligned frags, 2-way banks
#define FP 1    // parity of final step (139 & 1)

typedef __bf16 bf16x8 __attribute__((ext_vector_type(8)));
typedef __bf16 bf16x4 __attribute__((ext_vector_type(4)));
typedef float  f32x4  __attribute__((ext_vector_type(4)));

#define MFMA(a,b,c) __builtin_amdgcn_mfma_f32_16x16x32_bf16(a, b, c, 0, 0, 0)

__device__ __forceinline__ float fast_tanh(float a) {
    float e = __builtin_amdgcn_exp2f(a * 2.88539008178f);
    return 1.0f - 2.0f * __builtin_amdgcn_rcpf(e + 1.0f);
}

__device__ __forceinline__ void cvt_frag(const float* p, bf16x8& hi, bf16x8& lo) {
    f32x4 wa = *(const f32x4*)p;
    f32x4 wb = *(const f32x4*)(p + 4);
    #pragma unroll
    for (int j = 0; j < 8; ++j) {
        float f = (j < 4) ? wa[j] : wb[j - 4];
        __bf16 h = (__bf16)f;
        hi[j] = h;
        lo[j] = (__bf16)(f - (float)h);
    }
}

// 4 waves/block: waves 0-1 = layer0 (M=32 each), waves 2-3 = layer1 (M=32 each).
// Software pipeline: L0 computes step p while L1 computes step p-1.
// One barrier per phase; h state double-buffered by step parity.
__global__ __launch_bounds__(256, 2)
void rnn_kernel(const float* __restrict__ x,
                const float* __restrict__ h_state,
                const float* __restrict__ W_ih0,
                const float* __restrict__ W_hh0,
                const float* __restrict__ b_ih0,
                const float* __restrict__ b_hh0,
                const float* __restrict__ W_ih1,
                const float* __restrict__ W_hh1,
                const float* __restrict__ b_ih1,
                const float* __restrict__ b_hh1,
                const float* __restrict__ W_out,
                const float* __restrict__ b_out,
                float* __restrict__ out)
{
    __shared__ __align__(16) __bf16 h0hi[2][BT * HS], h0lo[2][BT * HS];
    __shared__ __align__(16) __bf16 h1hi[2][BT * HS], h1lo[2][BT * HS];
    __shared__ float xs[TT * 17];     // x staged [t][b]
    __shared__ float outs[TT * 17];   // y staged [t][b]
    __shared__ float pp[2][2][20];    // projection partials [parity][l1-wave][batch]

    const int tid  = threadIdx.x;
    const int w    = tid >> 6;        // 0..3
    const int grp  = w >> 1;          // 0 = layer0, 1 = layer1
    const int wl   = w & 1;           // unit half: units 32*wl .. 32*wl+31
    const int lane = tid & 63;
    const int col  = lane & 15;       // MFMA col (batch)
    const int q    = lane >> 4;       // quad
    const int b0   = blockIdx.x * BT;

    // ---- A-fragments (resident all 140 steps). mm = m-tile within this wave.
    // grp0: A_h/A_l [mm][kt<2] = W_hh0.  grp1: kt0-1 = W_ih1, kt2-3 = W_hh1.
    bf16x8 A_h[2][4], A_l[2][4];
    #pragma unroll
    for (int mm = 0; mm < 2; ++mm) {
        const int mt = 2 * wl + mm;
        #pragma unroll
        for (int kt = 0; kt < 2; ++kt) {
            const int off = (16 * mt + col) * HH + 32 * kt + 8 * q;
            if (grp == 0) {
                cvt_frag(W_hh0 + off, A_h[mm][kt], A_l[mm][kt]);
            } else {
                cvt_frag(W_ih1 + off, A_h[mm][kt],     A_l[mm][kt]);
                cvt_frag(W_hh1 + off, A_h[mm][kt + 2], A_l[mm][kt + 2]);
            }
        }
    }
    // epilogue scalars: grp0: e0=bias0, e1=Wih0 ; grp1: e0=bias1, e1=Wout
    float e0[2][4], e1[2][4];
    #pragma unroll
    for (int mm = 0; mm < 2; ++mm) {
        #pragma unroll
        for (int r = 0; r < 4; ++r) {
            int j = 16 * (2 * wl + mm) + 4 * q + r;
            if (grp == 0) { e0[mm][r] = b_ih0[j] + b_hh0[j]; e1[mm][r] = W_ih0[j]; }
            else          { e0[mm][r] = b_ih1[j] + b_hh1[j]; e1[mm][r] = W_out[j]; }
        }
    }
    const float bout = b_out[0];

    // ---- stage x into LDS [t][b] ----
    for (int c = 0; c < (TT * BT + 255) / 256; ++c) {
        int i = c * 256 + tid;
        if (i < TT * BT) {
            int t = i >> 4, b = i & 15;
            xs[t * 17 + b] = x[(size_t)(b0 + b) * TT + t];
        }
    }
    // ---- init hidden state into parity-1 buffers (step "-1") ----
    #pragma unroll
    for (int c = 0; c < (BT * HH) / 256; ++c) {
        int i = c * 256 + tid;
        int b = i >> 6, u = i & 63;
        float v0 = h_state[(size_t)(b0 + b) * HH + u];
        float v1 = h_state[(size_t)BB * HH + (size_t)(b0 + b) * HH + u];
        __bf16 c0 = (__bf16)v0;
        h0hi[1][b * HS + u] = c0;
        h0lo[1][b * HS + u] = (__bf16)(v0 - (float)c0);
        __bf16 c1 = (__bf16)v1;
        h1hi[1][b * HS + u] = c1;
        h1lo[1][b * HS + u] = (__bf16)(v1 - (float)c1);
    }
    __syncthreads();

    // per-lane fragment offsets (elements); all per-phase addressing is imm-offset
    const int fb = col * HS + 8 * q;          // + 32*kt for kt frag
    const int wbase = col * HS + 32 * wl + 4 * q;  // + 16*mm for writes

    auto do_phase = [&](int p, int PAR) {
        if (grp == 0) {
            if (p < TT) {
                // layer0 step p: read h0(p-1)@(1-PAR), write h0(p)@PAR
                bf16x8 bh[2], bl[2];
                #pragma unroll
                for (int kt = 0; kt < 2; ++kt) {
                    bh[kt] = *(const bf16x8*)(&h0hi[1 - PAR][fb + 32 * kt]);
                    bl[kt] = *(const bf16x8*)(&h0lo[1 - PAR][fb + 32 * kt]);
                }
                float xt = xs[p * 17 + col];
                #pragma unroll
                for (int mm = 0; mm < 2; ++mm) {
                    f32x4 c0 = {0,0,0,0}, c1 = {0,0,0,0}, c2 = {0,0,0,0};
                    #pragma unroll
                    for (int kt = 0; kt < 2; ++kt) {
                        c0 = MFMA(A_h[mm][kt], bh[kt], c0);   // hi*hi
                        c1 = MFMA(A_h[mm][kt], bl[kt], c1);   // hi*lo
                        c2 = MFMA(A_l[mm][kt], bh[kt], c2);   // lo*hi
                    }
                    f32x4 a = c0 + (c1 + c2);
                    bf16x4 hi4, lo4;
                    #pragma unroll
                    for (int r = 0; r < 4; ++r) {
                        float pre = a[r] + e0[mm][r] + e1[mm][r] * xt;
                        float hn  = fast_tanh(pre);
                        __bf16 h  = (__bf16)hn;
                        hi4[r] = h;
                        lo4[r] = (__bf16)(hn - (float)h);
                    }
                    *(bf16x4*)(&h0hi[PAR][wbase + 16 * mm]) = hi4;
                    *(bf16x4*)(&h0lo[PAR][wbase + 16 * mm]) = lo4;
                }
            }
            // folder (wave 0): fold step p-2 partials (written last phase @PAR)
            if (w == 0 && p >= 2 && lane < 16)
                outs[(p - 2) * 17 + lane] = pp[PAR][0][lane] + pp[PAR][1][lane] + bout;
        } else {
            if (p >= 1 && p <= TT) {
                // layer1 step s=p-1: read h0n(s)@(1-PAR), h1(s-1)@PAR; write h1(s)@(1-PAR)
                bf16x8 ch[4], cl[4];
                #pragma unroll
                for (int kt = 0; kt < 2; ++kt) {
                    ch[kt]     = *(const bf16x8*)(&h0hi[1 - PAR][fb + 32 * kt]);
                    cl[kt]     = *(const bf16x8*)(&h0lo[1 - PAR][fb + 32 * kt]);
                    ch[kt + 2] = *(const bf16x8*)(&h1hi[PAR][fb + 32 * kt]);
                    cl[kt + 2] = *(const bf16x8*)(&h1lo[PAR][fb + 32 * kt]);
                }
                float pr = 0.f;
                #pragma unroll
                for (int mm = 0; mm < 2; ++mm) {
                    f32x4 c0 = {0,0,0,0}, c1 = {0,0,0,0}, c2 = {0,0,0,0};
                    #pragma unroll
                    for (int kt = 0; kt < 4; ++kt) {
                        c0 = MFMA(A_h[mm][kt], ch[kt], c0);
                        c1 = MFMA(A_h[mm][kt], cl[kt], c1);
                        c2 = MFMA(A_l[mm][kt], ch[kt], c2);
                    }
                    f32x4 a = c0 + (c1 + c2);
                    bf16x4 hi4, lo4;
                    #pragma unroll
                    for (int r = 0; r < 4; ++r) {
                        float pre = a[r] + e0[mm][r];
                        float hn  = fast_tanh(pre);
                        pr += hn * e1[mm][r];
                        __bf16 h = (__bf16)hn;
                        hi4[r] = h;
                        lo4[r] = (__bf16)(hn - (float)h);
                    }
                    *(bf16x4*)(&h1hi[1 - PAR][wbase + 16 * mm]) = hi4;
                    *(bf16x4*)(&h1lo[1 - PAR][wbase + 16 * mm]) = lo4;
                }
                pr += __shfl_xor(pr, 16, 64);
                pr += __shfl_xor(pr, 32, 64);
                if (lane < 16) pp[1 - PAR][wl][lane] = pr;
            }
        }
    };

    // phases p = 0..TT+1 (142, even count), parity as literal for const-folding
    #pragma unroll 1
    for (int pb = 0; pb < TT + 2; pb += 2) {
        do_phase(pb, 0);
        __syncthreads();
        do_phase(pb + 1, 1);
        __syncthreads();
    }

    // ---- epilogue: staged y -> global; wave w does batches w,4+w,8+w,12+w ----
    #pragma unroll
    for (int bq = 0; bq < 4; ++bq) {
        int b = 4 * bq + w;
        #pragma unroll
        for (int c = 0; c < 3; ++c) {
            int t = c * 64 + lane;
            if (t < TT) out[(size_t)(b0 + b) * TT + t] = outs[t * 17 + b];
        }
    }
    // ---- h_final: [2,B,H] appended after out[B*T]; final parity FP=1 ----
    const size_t OFF = (size_t)BB * TT;
    #pragma unroll
    for (int c = 0; c < (BT * HH) / 256; ++c) {
        int i = c * 256 + tid;
        int b = i >> 6, u = i & 63;
        float v0 = (float)h0hi[FP][b * HS + u] + (float)h0lo[FP][b * HS + u];
        float v1 = (float)h1hi[FP][b * HS + u] + (float)h1lo[FP][b * HS + u];
        out[OFF + (size_t)(b0 + b) * HH + u] = v0;
        out[OFF + (size_t)BB * HH + (size_t)(b0 + b) * HH + u] = v1;
    }
}

extern "C" void kernel_launch(void* const* d_in, const int* in_sizes, int n_in,
                              void* d_out, int out_size, void* d_ws, size_t ws_size,
                              hipStream_t stream) {
    const float* x      = (const float*)d_in[0];
    const float* hst    = (const float*)d_in[1];
    const float* W_ih0  = (const float*)d_in[2];
    const float* W_hh0  = (const float*)d_in[3];
    const float* b_ih0  = (const float*)d_in[4];
    const float* b_hh0  = (const float*)d_in[5];
    const float* W_ih1  = (const float*)d_in[6];
    const float* W_hh1  = (const float*)d_in[7];
    const float* b_ih1  = (const float*)d_in[8];
    const float* b_hh1  = (const float*)d_in[9];
    const float* W_out  = (const float*)d_in[10];
    const float* b_outp = (const float*)d_in[11];
    float* out = (float*)d_out;

    dim3 grid(BB / BT);   // 512 blocks x 4 waves = 2048 waves (8/CU, 2 blk/CU)
    dim3 block(256);
    rnn_kernel<<<grid, block, 0, stream>>>(x, hst, W_ih0, W_hh0, b_ih0, b_hh0,
                                           W_ih1, W_hh1, b_ih1, b_hh1,
                                           W_out, b_outp, out);
}